// Round 6
// baseline (263.547 us; speedup 1.0000x reference)
//
#include <hip/hip_runtime.h>

// YOLO loss: S=14, B=2, C=20, N_CH=30, batch=4096
// pred, target: (4096, 14, 14, 30) float32. Output: scalar float32.
//
// R6: falsify the "phase-gap" hypothesis. Persistent, barrier-free,
// LDS-free kernel: 448 blocks x 256 threads (all co-resident), 7 cells
// per thread, depth-1 register pipeline (issue next cell's loads, compute
// current). Nothing ever drains vmcnt at a barrier. NT loads as an
// L3-policy probe. If this still delivers ~2.4 TB/s, the read-return
// ceiling is structural (H1) -> roofline.
//
// Cross-round delivery evidence (193 MB / stage1 time):
//   R0 2.39 | R2 2.35 | R4 2.28 | R5 2.40 TB/s  -- invariant to
//   coalescing, occupancy 20-58%, barriers, VGPR-vs-DMA return path.

#define SDIM 14
#define NCH  30
#define BATCH 4096
#define NCELLS (BATCH * SDIM * SDIM)     // 802816
#define L_COORD 5.0f
#define L_NOOBJ 0.5f

#define BLOCKS 448
#define THREADS 256
#define NTHREADS_TOT (BLOCKS * THREADS)  // 114688
#define CPT 7                            // cells per thread: 114688*7 = 802816
#define F2_PER_CELL 15                   // 30 floats = 15 float2
#define F2_STRIDE ((size_t)NTHREADS_TOT * F2_PER_CELL)  // float2 step between a thread's cells

typedef float vf2 __attribute__((ext_vector_type(2)));

__device__ __forceinline__ float cell_loss30(const float* __restrict__ pv,
                                             const float* __restrict__ tv)
{
    const float invS = 1.0f / (float)SDIM;
    float m  = (tv[4] > 0.0f) ? 1.0f : 0.0f;
    float nm = 1.0f - m;

    // target box 0 -> xyxy
    float tcx = tv[0] * invS, tcy = tv[1] * invS;
    float tw  = tv[2],        th  = tv[3];
    float tx1 = tcx - 0.5f * tw, ty1 = tcy - 0.5f * th;
    float tx2 = tcx + 0.5f * tw, ty2 = tcy + 0.5f * th;
    float ta  = (tx2 - tx1) * (ty2 - ty1);

    float iou[2];
    #pragma unroll
    for (int b = 0; b < 2; ++b) {
        float cx = pv[5*b + 0] * invS, cy = pv[5*b + 1] * invS;
        float w  = pv[5*b + 2],        h  = pv[5*b + 3];
        float x1 = cx - 0.5f * w, y1 = cy - 0.5f * h;
        float x2 = cx + 0.5f * w, y2 = cy + 0.5f * h;
        float lx = fmaxf(x1, tx1), ly = fmaxf(y1, ty1);
        float rx = fminf(x2, tx2), ry = fminf(y2, ty2);
        float iw = fmaxf(rx - lx, 0.0f);
        float ih = fmaxf(ry - ly, 0.0f);
        float inter = iw * ih;
        float pa = (x2 - x1) * (y2 - y1);
        iou[b] = inter / (pa + ta - inter);
    }

    // argmax (first-wins on ties, matching jnp.argmax).
    // Responsible-box select via explicit ternaries: no dynamically-indexed
    // array -> nothing the compiler can spill (R4 lesson).
    bool sel = (iou[1] > iou[0]);
    float max_iou = sel ? iou[1] : iou[0];

    float rpx = sel ? pv[5] : pv[0];
    float rpy = sel ? pv[6] : pv[1];
    float rpw = sel ? pv[7] : pv[2];
    float rph = sel ? pv[8] : pv[3];
    float rpc = sel ? pv[9] : pv[4];
    float rtx = sel ? tv[5] : tv[0];
    float rty = sel ? tv[6] : tv[1];
    float rtw = sel ? tv[7] : tv[2];
    float rth = sel ? tv[8] : tv[3];

    float dxy = (rpx - rtx) * (rpx - rtx) + (rpy - rty) * (rpy - rty);
    float sw  = sqrtf(rpw) - sqrtf(rtw);
    float sh  = sqrtf(rph) - sqrtf(rth);
    float dwh = sw * sw + sh * sh;
    float dob = (rpc - max_iou) * (rpc - max_iou);

    float dcls = 0.0f;
    #pragma unroll
    for (int c = 10; c < NCH; ++c) {
        float d = pv[c] - tv[c];
        dcls += d * d;
    }

    float d4 = pv[4] - tv[4];
    float d9 = pv[9] - tv[9];
    float dnoobj = d4 * d4 + d9 * d9;

    return m * (L_COORD * (dxy + dwh) + dob + dcls) + nm * L_NOOBJ * dnoobj;
}

__global__ __launch_bounds__(THREADS) void yolo_loss_stage1(
    const float* __restrict__ pred,
    const float* __restrict__ tgt,
    float* __restrict__ partial)
{
    const int tid = threadIdx.x;
    const int f   = blockIdx.x * THREADS + tid;   // 0..114687

    const vf2* p2 = (const vf2*)pred;
    const vf2* t2 = (const vf2*)tgt;

    // Thread's cell j (j=0..6) starts at float2 index f*15 + j*F2_STRIDE.
    size_t base = (size_t)f * F2_PER_CELL;

    vf2 A[2 * F2_PER_CELL];   // current cell: [0,15) pred, [15,30) tgt
    vf2 B[2 * F2_PER_CELL];   // prefetch of next cell

    #pragma unroll
    for (int i = 0; i < F2_PER_CELL; ++i) {
        A[i]               = __builtin_nontemporal_load(p2 + base + i);
        A[F2_PER_CELL + i] = __builtin_nontemporal_load(t2 + base + i);
    }

    float sum = 0.0f;

    #pragma unroll 1
    for (int j = 0; j < CPT; ++j) {
        if (j < CPT - 1) {
            size_t nb = base + (size_t)(j + 1) * F2_STRIDE;
            #pragma unroll
            for (int i = 0; i < F2_PER_CELL; ++i) {
                B[i]               = __builtin_nontemporal_load(p2 + nb + i);
                B[F2_PER_CELL + i] = __builtin_nontemporal_load(t2 + nb + i);
            }
        }

        float pv[NCH], tv[NCH];
        #pragma unroll
        for (int i = 0; i < F2_PER_CELL; ++i) {
            pv[2*i] = A[i][0];               pv[2*i+1] = A[i][1];
            tv[2*i] = A[F2_PER_CELL + i][0]; tv[2*i+1] = A[F2_PER_CELL + i][1];
        }
        sum += cell_loss30(pv, tv);

        if (j < CPT - 1) {
            #pragma unroll
            for (int i = 0; i < 2 * F2_PER_CELL; ++i) A[i] = B[i];
        }
    }

    // Reduction: wave shuffle (64) -> LDS -> one partial per block
    #pragma unroll
    for (int off = 32; off > 0; off >>= 1)
        sum += __shfl_down(sum, off, 64);

    __shared__ float wsum[4];
    int lane = tid & 63;
    int wid  = tid >> 6;
    if (lane == 0) wsum[wid] = sum;
    __syncthreads();
    if (tid == 0)
        partial[blockIdx.x] = wsum[0] + wsum[1] + wsum[2] + wsum[3];
}

__global__ __launch_bounds__(256) void yolo_loss_stage2(
    const float* __restrict__ partial,
    float* __restrict__ out)
{
    const int tid = threadIdx.x;
    float s = 0.0f;
    for (int i = tid; i < BLOCKS; i += 256) s += partial[i];

    #pragma unroll
    for (int off = 32; off > 0; off >>= 1)
        s += __shfl_down(s, off, 64);

    __shared__ float wsum[4];
    int lane = tid & 63;
    int wid  = tid >> 6;
    if (lane == 0) wsum[wid] = s;
    __syncthreads();
    if (tid == 0)
        out[0] = (wsum[0] + wsum[1] + wsum[2] + wsum[3]) * (1.0f / (float)BATCH);
}

extern "C" void kernel_launch(void* const* d_in, const int* in_sizes, int n_in,
                              void* d_out, int out_size, void* d_ws, size_t ws_size,
                              hipStream_t stream)
{
    const float* pred = (const float*)d_in[0];
    const float* tgt  = (const float*)d_in[1];
    float* out        = (float*)d_out;
    float* partial    = (float*)d_ws;   // 448 floats

    hipLaunchKernelGGL(yolo_loss_stage1, dim3(BLOCKS), dim3(THREADS), 0, stream,
                       pred, tgt, partial);
    hipLaunchKernelGGL(yolo_loss_stage2, dim3(1), dim3(256), 0, stream,
                       partial, out);
}